// Round 9
// baseline (186.344 us; speedup 1.0000x reference)
//
#include <hip/hip_runtime.h>
#include <hip/hip_bf16.h>
#include <math.h>

#define B_ 2
#define T_ 2048
#define C_ 1024
#define NH_ 16
#define HS_ 64
#define BD_ 16
#define DELTA 64

typedef __attribute__((ext_vector_type(8))) short bf16x8_t;
typedef __attribute__((ext_vector_type(4))) float f32x4_t;
typedef __attribute__((address_space(1))) const unsigned int GUI;
typedef __attribute__((address_space(3))) unsigned int LUI;

__device__ __forceinline__ unsigned short f2bf(float f) {
    unsigned u = __float_as_uint(f);
    u = u + 0x7fffu + ((u >> 16) & 1u);
    return (unsigned short)(u >> 16);
}
__device__ __forceinline__ float bf2f(unsigned short h) {
    return __uint_as_float(((unsigned)h) << 16);
}
__device__ __forceinline__ void glds16(const unsigned short* g, unsigned short* l) {
    __builtin_amdgcn_global_load_lds((GUI*)g, (LUI*)l, 16, 0, 0);
}

// ---- prep: cvt (x, W_val, c_proj) + W_comb + cbuf, one launch ----
__global__ __launch_bounds__(256) void prep_kernel(
    const float* __restrict__ x, const float* __restrict__ wval,
    const float* __restrict__ cproj, const float* __restrict__ Wd,
    const float* __restrict__ sfw, const float* __restrict__ rel,
    const float* __restrict__ ppw, const float* __restrict__ sfb,
    unsigned short* __restrict__ xb, unsigned short* __restrict__ wvalb,
    unsigned short* __restrict__ cprojb, unsigned short* __restrict__ wc,
    float* __restrict__ cbuf)
{
    const int bid = blockIdx.x;
    if (bid < 6144) {           // fp32 -> bf16 conversions
        const long long NX = (long long)B_*T_*C_;
        const long long NW = (long long)C_*C_;
        long long e = ((long long)bid * 256 + threadIdx.x) * 4;
        const float* src; unsigned short* dst; long long off;
        if (e < NX)            { src = x;     dst = xb;     off = e; }
        else if (e < NX + NW)  { src = wval;  dst = wvalb;  off = e - NX; }
        else                   { src = cproj; dst = cprojb; off = e - NX - NW; }
        float4 v = *(const float4*)(src + off);
        ushort4 o;
        o.x = f2bf(v.x); o.y = f2bf(v.y); o.z = f2bf(v.z); o.w = f2bf(v.w);
        *(ushort4*)(dst + off) = o;
    } else if (bid < 8192) {    // W_comb
        int idx = (bid - 6144) * 256 + threadIdx.x;
        int c = idx & 1023, row = idx >> 10;
        int h = row >> 5, j = row & 31;
        float s = 0.f;
        #pragma unroll
        for (int d = 0; d < 16; ++d) s += sfw[j*16 + d] * Wd[(h*16 + d)*1024 + c];
        wc[idx] = f2bf(s);
    } else {                    // cbuf[w][j<16] = posfeat+sfb ; [16+j] = sfb
        for (int e = threadIdx.x; e < 64*32; e += 256) {
            int w_ = e >> 5, j = e & 31;
            float s = sfb[j];
            if (j < 16) {
                #pragma unroll
                for (int d = 0; d < 16; ++d) s += rel[w_*16 + d] * ppw[j*16 + d];
            }
            cbuf[e] = s;
        }
    }
}

// ---- 128x128 tile GEMM, BK=64, m97 layout, XCD-swizzled flat grid ----
// MODE 0: fp32 out (Cf, pitch N). MODE 2: split col<512 -> Cb1 bf16 pitch 512,
// col>=512 -> Cb2 bf16 pitch 1024.
template<int MODE>
__global__ __launch_bounds__(256) void gemm128(
    const unsigned short* __restrict__ A,
    const unsigned short* __restrict__ Bw,
    float* __restrict__ Cf, unsigned short* __restrict__ Cb1,
    unsigned short* __restrict__ Cb2,
    int M, int N, int K, int nxt)
{
    __shared__ unsigned short As[128*64];   // 16 KB
    __shared__ unsigned short Bs[128*64];   // 16 KB
    const int nblk = gridDim.x;
    const int bid = blockIdx.x;
    const int l = (bid & 7) * (nblk >> 3) + (bid >> 3);   // XCD-contiguous
    const int nb = l % nxt, mb = l / nxt;
    const int m0 = mb * 128, n0 = nb * 128;
    const int tid = threadIdx.x;
    const int lane = tid & 63;
    const int wid = tid >> 6;
    const int waveM = wid >> 1, waveN = wid & 1;
    const int row16 = lane & 15, quad = lane >> 4;
    const int wbase = wid * 512;   // ushort offset of this wave's chunk group

    long long gA[4], gB[4];
    #pragma unroll
    for (int q = 0; q < 4; ++q) {
        int c = q*256 + tid, r = c >> 3, col = (c & 7) * 8;
        gA[q] = (long long)(m0 + r) * K + col;
        gB[q] = (long long)(n0 + r) * K + col;
    }

    f32x4_t acc[4][4];
    #pragma unroll
    for (int i = 0; i < 4; ++i)
        #pragma unroll
        for (int j = 0; j < 4; ++j) { f32x4_t z = {0.f,0.f,0.f,0.f}; acc[i][j] = z; }

    for (int k0 = 0; k0 < K; k0 += 64) {
        #pragma unroll
        for (int q = 0; q < 4; ++q) {
            glds16(A  + gA[q] + k0, As + q*2048 + wbase);
            glds16(Bw + gB[q] + k0, Bs + q*2048 + wbase);
        }
        __syncthreads();
        #pragma unroll
        for (int kk = 0; kk < 2; ++kk) {
            bf16x8_t af[4], bfv[4];
            #pragma unroll
            for (int mt = 0; mt < 4; ++mt)
                af[mt] = *(const bf16x8_t*)(As + (waveM*64 + mt*16 + row16)*64
                                               + (kk*4 + quad)*8);
            #pragma unroll
            for (int nt = 0; nt < 4; ++nt)
                bfv[nt] = *(const bf16x8_t*)(Bs + (waveN*64 + nt*16 + row16)*64
                                                + (kk*4 + quad)*8);
            #pragma unroll
            for (int mt = 0; mt < 4; ++mt)
                #pragma unroll
                for (int nt = 0; nt < 4; ++nt)
                    acc[mt][nt] = __builtin_amdgcn_mfma_f32_16x16x32_bf16(
                        af[mt], bfv[nt], acc[mt][nt], 0, 0, 0);
        }
        __syncthreads();
    }
    #pragma unroll
    for (int mt = 0; mt < 4; ++mt)
        #pragma unroll
        for (int nt = 0; nt < 4; ++nt) {
            int col = n0 + waveN*64 + nt*16 + row16;
            #pragma unroll
            for (int rr = 0; rr < 4; ++rr) {
                int row = m0 + waveM*64 + mt*16 + quad*4 + rr;
                float v = acc[mt][nt][rr];
                if (MODE == 0) {
                    Cf[(long long)row * N + col] = v;
                } else {
                    if (col < 512) Cb1[(long long)row * 512 + col] = f2bf(v);
                    else           Cb2[(long long)row * 1024 + (col - 512)] = f2bf(v);
                }
            }
        }
}

// ---- windowed attention v9: bf16 projL pitch 40, quadratic gelu ----
__global__ __launch_bounds__(256, 3) void attn_kernel(
    const unsigned short* __restrict__ projb,  // (B*T, 512) bf16
    const unsigned short* __restrict__ valb,   // (B*T, 1024) bf16
    const float* __restrict__ cbuf,            // (64,32): posfeat+sfb | sfb
    const float* __restrict__ bw,              // (16,)
    const float* __restrict__ dw,              // (16,)
    const float* __restrict__ db,              // (1,)
    unsigned short* __restrict__ attb)         // (B*T, 1024) bf16
{
    __shared__ __align__(16) unsigned short projL[127*40];  // 10160 B, pitch 80B
    __shared__ __align__(16) unsigned short valL[128*66];   // 16896 B, row 127 zeroed
    __shared__ __align__(16) unsigned short wgtA[64*136];   // 17408 B, holds exp()
    __shared__ float smL[4*64];
    const int t0 = blockIdx.x * 64;
    const int h = blockIdx.y, b = blockIdx.z;
    const int tid = threadIdx.x;
    const int lane = tid & 63, wid = tid >> 6;

    for (int e = tid; e < 1088; e += 256) ((uint4*)wgtA)[e] = make_uint4(0,0,0,0);
    for (int e = tid; e < 128*16; e += 256) {
        int ls = e >> 4, d4 = e & 15;
        int s = t0 - 63 + ls;
        ushort4 v = make_ushort4(0, 0, 0, 0);
        if (s >= 0 && ls < 127)
            v = *(const ushort4*)(valb + (long long)(b*T_ + s)*1024 + h*64 + d4*4);
        *(ushort4*)(valL + ls*66 + d4*4) = v;
    }
    // projL rows: 4 x 16B chunks per row, pitch 40 ushorts
    for (int e = tid; e < 127*4; e += 256) {
        int r = e >> 2, c = e & 3;
        int s = t0 - 63 + r;
        uint4 v = make_uint4(0, 0, 0, 0);
        if (s >= 0)
            v = *(const uint4*)(projb + (long long)(b*T_ + s)*512 + h*32 + c*8);
        *(uint4*)(projL + r*40 + c*8) = v;
    }
    // per-lane scaled weights (loop-invariant)
    float bwh[16], bwp[16], dwh[16], dwp[16];
    #pragma unroll
    for (int j = 0; j < 16; ++j) {
        float bj = bw[j], dj = dw[j];
        bwh[j] = 0.5f*bj; bwp[j] = 0.39894228f*bj;
        dwh[j] = 0.5f*dj; dwp[j] = 0.39894228f*dj;
    }
    const float db0 = db[0];
    const int tl63 = t0 + lane - 63;
    __syncthreads();

    // t-row (t = t0+lane) into 32 VGPRs
    float tv[32];
    {
        const int r = lane + 63;
        #pragma unroll
        for (int g = 0; g < 4; ++g) {
            bf16x8_t v = *(const bf16x8_t*)(projL + r*40 + g*8);
            #pragma unroll
            for (int k = 0; k < 8; ++k) tv[8*g + k] = bf2f((unsigned short)v[k]);
        }
    }

    float sm = 0.f;
    #pragma unroll
    for (int it = 0; it < 16; ++it) {
        const int w = __builtin_amdgcn_readfirstlane(wid*16 + it);  // uniform
        const float* cbw = cbuf + w*32;        // uniform -> scalar loads
        const int r = lane + w;
        bf16x8_t sv[4];
        #pragma unroll
        for (int g = 0; g < 4; ++g)
            sv[g] = *(const bf16x8_t*)(projL + r*40 + g*8);
        float bond = 0.f, dam = 0.f;
        #pragma unroll
        for (int g = 0; g < 2; ++g) {          // bond feats j = 8g..8g+7
            #pragma unroll
            for (int k = 0; k < 8; ++k) {
                int j = 8*g + k;
                float z = bf2f((unsigned short)sv[g][k]) - tv[j] + cbw[j];
                float z2 = fminf(z*z, 1.0f);   // safety clamp (|z| < ~0.5)
                bond = fmaf(z,  bwh[j], bond);
                bond = fmaf(z2, bwp[j], bond);
            }
        }
        #pragma unroll
        for (int g = 0; g < 2; ++g) {          // damage feats
            #pragma unroll
            for (int k = 0; k < 8; ++k) {
                int j = 8*g + k;
                float z = bf2f((unsigned short)sv[g+2][k]) - tv[16+j] + cbw[16+j];
                float z2 = fminf(z*z, 1.0f);
                dam = fmaf(z,  dwh[j], dam);
                dam = fmaf(z2, dwp[j], dam);
            }
        }
        float damage = __builtin_amdgcn_rcpf(1.f + __expf(-(dam + db0)));
        bool valid = (tl63 + w) >= 0;
        float ex = valid ? __expf(bond - 10.f*damage) : 0.f;
        sm += ex;
        wgtA[lane*136 + lane + w] = f2bf(ex);  // unnormalized
    }
    smL[wid*64 + lane] = sm;
    __syncthreads();

    // stage 3: out(64t x 64d) = wgtA(64x128) @ valL(128x64), banded MFMA
    const int waveM = wid >> 1, waveN = wid & 1;
    const int row16 = lane & 15, quad = lane >> 4;
    f32x4_t acc[2][2];
    #pragma unroll
    for (int i = 0; i < 2; ++i)
        #pragma unroll
        for (int j = 0; j < 2; ++j) { f32x4_t z = {0.f,0.f,0.f,0.f}; acc[i][j] = z; }
    #pragma unroll
    for (int kk = 0; kk < 3; ++kk) {
        const int k0 = waveM*32 + kk*32;
        bf16x8_t af[2], bfv[2];
        #pragma unroll
        for (int mt = 0; mt < 2; ++mt)
            af[mt] = *(const bf16x8_t*)(wgtA + (waveM*32 + mt*16 + row16)*136 + k0 + quad*8);
        #pragma unroll
        for (int nt = 0; nt < 2; ++nt) {
            int d = waveN*32 + nt*16 + row16;
            bf16x8_t bv;
            #pragma unroll
            for (int j = 0; j < 8; ++j)
                bv[j] = (short)valL[(k0 + quad*8 + j)*66 + d];
            bfv[nt] = bv;
        }
        #pragma unroll
        for (int mt = 0; mt < 2; ++mt)
            #pragma unroll
            for (int nt = 0; nt < 2; ++nt)
                acc[mt][nt] = __builtin_amdgcn_mfma_f32_16x16x32_bf16(
                    af[mt], bfv[nt], acc[mt][nt], 0, 0, 0);
    }
    #pragma unroll
    for (int mt = 0; mt < 2; ++mt)
        #pragma unroll
        for (int nt = 0; nt < 2; ++nt) {
            int d = waveN*32 + nt*16 + row16;
            #pragma unroll
            for (int rr = 0; rr < 4; ++rr) {
                int trel = waveM*32 + mt*16 + quad*4 + rr;
                float smt = smL[trel] + smL[64 + trel] + smL[128 + trel] + smL[192 + trel];
                float v = acc[mt][nt][rr] * __builtin_amdgcn_rcpf(smt);
                attb[((long long)(b*T_ + t0 + trel))*1024 + h*64 + d] = f2bf(v);
            }
        }
}

extern "C" void kernel_launch(void* const* d_in, const int* in_sizes, int n_in,
                              void* d_out, int out_size, void* d_ws, size_t ws_size,
                              hipStream_t stream) {
    const float* x    = (const float*)d_in[0];
    const float* Wd   = (const float*)d_in[1];
    const float* Wv   = (const float*)d_in[2];
    const float* rel  = (const float*)d_in[3];
    const float* sfw  = (const float*)d_in[4];
    const float* sfb  = (const float*)d_in[5];
    const float* ppw  = (const float*)d_in[6];
    const float* bow  = (const float*)d_in[7];
    const float* dow  = (const float*)d_in[8];
    const float* dob  = (const float*)d_in[9];
    const float* cpw  = (const float*)d_in[10];
    float* out = (float*)d_out;

    char* w = (char*)d_ws;
    unsigned short* xb      = (unsigned short*)(w);                 // 8,388,608 B
    unsigned short* wcat    = (unsigned short*)(w + 8388608);       // 3,145,728 B
    unsigned short* cprojb  = (unsigned short*)(w + 11534336);      // 2,097,152 B
    float*          cbuf    = (float*)         (w + 13631488);      //     8,192 B
    unsigned short* projb   = (unsigned short*)(w + 13639680);      // 4,194,304 B (bf16)
    unsigned short* valb    = (unsigned short*)(w + 17833984);      // 8,388,608 B
    unsigned short* attb    = (unsigned short*)(w + 26222592);      // 8,388,608 B

    prep_kernel<<<8193, 256, 0, stream>>>(
        x, Wv, cpw, Wd, sfw, rel, ppw, sfb,
        xb, wcat + 512*1024, cprojb, wcat, cbuf);
    // [projb | valb] = x @ [W_comb; W_val]^T : 384 blocks, XCD-swizzled
    gemm128<2><<<384, 256, 0, stream>>>(
        xb, wcat, (float*)nullptr, projb, valb, B_*T_, 1536, C_, 12);
    attn_kernel<<<dim3(T_/64, NH_, B_), 256, 0, stream>>>(
        projb, valb, cbuf, bow, dow, dob, attb);
    // out = att @ c_proj^T : fp32, 256 blocks, XCD-swizzled
    gemm128<0><<<256, 256, 0, stream>>>(
        attb, cprojb, out, (unsigned short*)nullptr, (unsigned short*)nullptr,
        B_*T_, C_, C_, 8);
}

// Round 10
// 172.346 us; speedup vs baseline: 1.0812x; 1.0812x over previous
//
#include <hip/hip_runtime.h>
#include <hip/hip_bf16.h>
#include <math.h>

#define B_ 2
#define T_ 2048
#define C_ 1024
#define NH_ 16
#define HS_ 64
#define BD_ 16
#define DELTA 64
#define K2G 0.3989422804f   // gelu''(0)/2 = 1/sqrt(2*pi)

typedef __attribute__((ext_vector_type(8))) short bf16x8_t;
typedef __attribute__((ext_vector_type(4))) float f32x4_t;
typedef __attribute__((address_space(1))) const unsigned int GUI;
typedef __attribute__((address_space(3))) unsigned int LUI;

__device__ __forceinline__ unsigned short f2bf(float f) {
    unsigned u = __float_as_uint(f);
    u = u + 0x7fffu + ((u >> 16) & 1u);
    return (unsigned short)(u >> 16);
}
__device__ __forceinline__ float bf2f(unsigned short h) {
    return __uint_as_float(((unsigned)h) << 16);
}
__device__ __forceinline__ float bflo(unsigned u) { return __uint_as_float(u << 16); }
__device__ __forceinline__ float bfhi(unsigned u) { return __uint_as_float(u & 0xffff0000u); }
__device__ __forceinline__ void glds16(const unsigned short* g, unsigned short* l) {
    __builtin_amdgcn_global_load_lds((GUI*)g, (LUI*)l, 16, 0, 0);
}

// ---- prep: cvt + W_comb + per-w scalar constants ----
__global__ __launch_bounds__(256) void prep_kernel(
    const float* __restrict__ x, const float* __restrict__ wval,
    const float* __restrict__ cproj, const float* __restrict__ Wd,
    const float* __restrict__ sfw, const float* __restrict__ rel,
    const float* __restrict__ ppw, const float* __restrict__ sfb,
    const float* __restrict__ bw, const float* __restrict__ dw,
    const float* __restrict__ dob,
    unsigned short* __restrict__ xb, unsigned short* __restrict__ wvalb,
    unsigned short* __restrict__ cprojb, unsigned short* __restrict__ wc,
    float* __restrict__ cbuf2)
{
    const int bid = blockIdx.x;
    if (bid < 6144) {           // fp32 -> bf16
        const long long NX = (long long)B_*T_*C_;
        const long long NW = (long long)C_*C_;
        long long e = ((long long)bid * 256 + threadIdx.x) * 4;
        const float* src; unsigned short* dst; long long off;
        if (e < NX)            { src = x;     dst = xb;     off = e; }
        else if (e < NX + NW)  { src = wval;  dst = wvalb;  off = e - NX; }
        else                   { src = cproj; dst = cprojb; off = e - NX - NW; }
        float4 v = *(const float4*)(src + off);
        ushort4 o;
        o.x = f2bf(v.x); o.y = f2bf(v.y); o.z = f2bf(v.z); o.w = f2bf(v.w);
        *(ushort4*)(dst + off) = o;
    } else if (bid < 8192) {    // W_comb
        int idx = (bid - 6144) * 256 + threadIdx.x;
        int c = idx & 1023, row = idx >> 10;
        int h = row >> 5, j = row & 31;
        float s = 0.f;
        #pragma unroll
        for (int d = 0; d < 16; ++d) s += sfw[j*16 + d] * Wd[(h*16 + d)*1024 + c];
        wc[idx] = f2bf(s);
    } else {
        // cbuf2[w] = sum_j bw_j (0.5 c + K2 c^2), c = posfeat[w][j]+sfb[j]
        // cbuf2[64] = db0 + sum_j dw_j (0.5 c' + K2 c'^2), c' = sfb[16+j]
        int tid = threadIdx.x;
        if (tid < 64) {
            float acc = 0.f;
            for (int j = 0; j < 16; ++j) {
                float c = sfb[j];
                #pragma unroll
                for (int d = 0; d < 16; ++d) c += rel[tid*16 + d] * ppw[j*16 + d];
                acc += bw[j] * fmaf(K2G*c, c, 0.5f*c);
            }
            cbuf2[tid] = acc;
        } else if (tid == 64) {
            float acc = dob[0];
            for (int j = 0; j < 16; ++j) {
                float c = sfb[16 + j];
                acc += dw[j] * fmaf(K2G*c, c, 0.5f*c);
            }
            cbuf2[64] = acc;
        }
    }
}

// ---- 128x128 tile GEMM, BK=64, m97 layout, XCD-swizzled flat grid ----
template<int MODE>
__global__ __launch_bounds__(256) void gemm128(
    const unsigned short* __restrict__ A,
    const unsigned short* __restrict__ Bw,
    float* __restrict__ Cf, unsigned short* __restrict__ Cb1,
    unsigned short* __restrict__ Cb2,
    int M, int N, int K, int nxt)
{
    __shared__ unsigned short As[128*64];
    __shared__ unsigned short Bs[128*64];
    const int nblk = gridDim.x;
    const int bid = blockIdx.x;
    const int l = (bid & 7) * (nblk >> 3) + (bid >> 3);
    const int nb = l % nxt, mb = l / nxt;
    const int m0 = mb * 128, n0 = nb * 128;
    const int tid = threadIdx.x;
    const int lane = tid & 63;
    const int wid = tid >> 6;
    const int waveM = wid >> 1, waveN = wid & 1;
    const int row16 = lane & 15, quad = lane >> 4;
    const int wbase = wid * 512;

    long long gA[4], gB[4];
    #pragma unroll
    for (int q = 0; q < 4; ++q) {
        int c = q*256 + tid, r = c >> 3, col = (c & 7) * 8;
        gA[q] = (long long)(m0 + r) * K + col;
        gB[q] = (long long)(n0 + r) * K + col;
    }

    f32x4_t acc[4][4];
    #pragma unroll
    for (int i = 0; i < 4; ++i)
        #pragma unroll
        for (int j = 0; j < 4; ++j) { f32x4_t z = {0.f,0.f,0.f,0.f}; acc[i][j] = z; }

    for (int k0 = 0; k0 < K; k0 += 64) {
        #pragma unroll
        for (int q = 0; q < 4; ++q) {
            glds16(A  + gA[q] + k0, As + q*2048 + wbase);
            glds16(Bw + gB[q] + k0, Bs + q*2048 + wbase);
        }
        __syncthreads();
        #pragma unroll
        for (int kk = 0; kk < 2; ++kk) {
            bf16x8_t af[4], bfv[4];
            #pragma unroll
            for (int mt = 0; mt < 4; ++mt)
                af[mt] = *(const bf16x8_t*)(As + (waveM*64 + mt*16 + row16)*64
                                               + (kk*4 + quad)*8);
            #pragma unroll
            for (int nt = 0; nt < 4; ++nt)
                bfv[nt] = *(const bf16x8_t*)(Bs + (waveN*64 + nt*16 + row16)*64
                                                + (kk*4 + quad)*8);
            #pragma unroll
            for (int mt = 0; mt < 4; ++mt)
                #pragma unroll
                for (int nt = 0; nt < 4; ++nt)
                    acc[mt][nt] = __builtin_amdgcn_mfma_f32_16x16x32_bf16(
                        af[mt], bfv[nt], acc[mt][nt], 0, 0, 0);
        }
        __syncthreads();
    }
    #pragma unroll
    for (int mt = 0; mt < 4; ++mt)
        #pragma unroll
        for (int nt = 0; nt < 4; ++nt) {
            int col = n0 + waveN*64 + nt*16 + row16;
            #pragma unroll
            for (int rr = 0; rr < 4; ++rr) {
                int row = m0 + waveM*64 + mt*16 + quad*4 + rr;
                float v = acc[mt][nt][rr];
                if (MODE == 0) {
                    Cf[(long long)row * N + col] = v;
                } else {
                    if (col < 512) Cb1[(long long)row * 512 + col] = f2bf(v);
                    else           Cb2[(long long)row * 1024 + (col - 512)] = f2bf(v);
                }
            }
        }
}

// ---- windowed attention v10: bilinear decomposition of quadratic-gelu ----
__global__ __launch_bounds__(256, 3) void attn_kernel(
    const unsigned short* __restrict__ projb,  // (B*T, 512) bf16
    const unsigned short* __restrict__ valb,   // (B*T, 1024) bf16
    const float* __restrict__ cbuf2,           // [0..63] bond per-w const; [64] damage const
    const float* __restrict__ bw,              // (16,)
    const float* __restrict__ dw,              // (16,)
    unsigned short* __restrict__ attb)         // (B*T, 1024) bf16
{
    __shared__ __align__(16) unsigned char smem[53928];
    unsigned short* projL = (unsigned short*)(smem);            // 127x40 ush (phase<=A)
    unsigned short* Qb    = (unsigned short*)(smem + 10160);    // 128x16 ush (bw-weighted bond)
    unsigned short* Qd    = (unsigned short*)(smem + 14256);    // 128x16 ush (dw-weighted dmg)
    unsigned short* wgtA  = (unsigned short*)(smem);            // 64x136 ush (phase>=zeroing)
    unsigned short* valL  = (unsigned short*)(smem + 18352);    // 128x66 ush
    unsigned*       SbL   = (unsigned*)(smem + 35248);          // 64x65 dw: {S1,S2} bf16 pair
    uint2*          TbL   = (uint2*)(smem + 51888);             // 127 x {Lb,Db | Ld,Dd} bf16
    float*          smL   = (float*)(smem + 52904);             // 4x64
    const int t0 = blockIdx.x * 64;
    const int h = blockIdx.y, b = blockIdx.z;
    const int tid = threadIdx.x;
    const int lane = tid & 63, wid = tid >> 6;
    const int row16 = lane & 15, quad = lane >> 4;

    // ---- phase 1: stage projL + valL ----
    for (int e = tid; e < 128*16; e += 256) {
        int ls = e >> 4, d4 = e & 15;
        int s = t0 - 63 + ls;
        ushort4 v = make_ushort4(0, 0, 0, 0);
        if (s >= 0 && ls < 127)
            v = *(const ushort4*)(valb + (long long)(b*T_ + s)*1024 + h*64 + d4*4);
        *(ushort4*)(valL + ls*66 + d4*4) = v;
    }
    for (int e = tid; e < 127*4; e += 256) {
        int r = e >> 2, c = e & 3;
        int s = t0 - 63 + r;
        uint4 v = make_uint4(0, 0, 0, 0);
        if (s >= 0)
            v = *(const uint4*)(projb + (long long)(b*T_ + s)*512 + h*32 + c*8);
        *(uint4*)(projL + r*40 + c*8) = v;
    }
    __syncthreads();

    // ---- phase 2: row tables + weighted rows ----
    {   // Qb/Qd: thread -> (row, half)
        int r = tid >> 1, hf = tid & 1;
        bf16x8_t ob, od;
        if (r < 127) {
            bf16x8_t vb = *(const bf16x8_t*)(projL + r*40 + hf*8);
            bf16x8_t vd = *(const bf16x8_t*)(projL + r*40 + 16 + hf*8);
            #pragma unroll
            for (int k = 0; k < 8; ++k) {
                int j = hf*8 + k;
                ob[k] = (short)f2bf(bf2f((unsigned short)vb[k]) * bw[j]);
                od[k] = (short)f2bf(bf2f((unsigned short)vd[k]) * dw[j]);
            }
        } else {
            #pragma unroll
            for (int k = 0; k < 8; ++k) { ob[k] = 0; od[k] = 0; }
        }
        *(bf16x8_t*)(Qb + r*16 + hf*8) = ob;
        *(bf16x8_t*)(Qd + r*16 + hf*8) = od;
    }
    if (tid < 127) {
        int r = tid;
        float Lb = 0.f, Db = 0.f, Ld = 0.f, Dd = 0.f;
        #pragma unroll
        for (int g = 0; g < 4; ++g) {
            bf16x8_t v = *(const bf16x8_t*)(projL + r*40 + g*8);
            #pragma unroll
            for (int k = 0; k < 8; ++k) {
                float a = bf2f((unsigned short)v[k]);
                int j = g*8 + k;
                if (j < 16) { float wj = bw[j];     Lb += wj*a; Db += wj*a*a; }
                else        { float wj = dw[j-16];  Ld += wj*a; Dd += wj*a*a; }
            }
        }
        uint2 o;
        o.x = (unsigned)f2bf(Lb) | ((unsigned)f2bf(Db) << 16);
        o.y = (unsigned)f2bf(Ld) | ((unsigned)f2bf(Dd) << 16);
        TbL[r] = o;
    }
    __syncthreads();

    // ---- phase 3 (stage-A): S1/S2 via MFMA, banded write to SbL ----
    {
        const int trow = 63 + wid*16 + row16;         // projL row of t (A side)
        bf16x8_t afull = *(const bf16x8_t*)(projL + trow*40 + quad*8);  // k=quad*8..+7
        const bool loQ = quad < 2;
        #pragma unroll
        for (int ts = 0; ts < 6; ++ts) {
            const int sb = wid*16 + ts*16;
            if (sb >= 128) continue;                  // only wid=3, ts=5
            const int srow = sb + row16;
            bf16x8_t qb = *(const bf16x8_t*)(Qb + srow*16 + (quad & 1)*8);
            bf16x8_t qd = *(const bf16x8_t*)(Qd + srow*16 + (quad & 1)*8);
            bf16x8_t b1, b2;
            #pragma unroll
            for (int k = 0; k < 8; ++k) {
                b1[k] = loQ ? qb[k] : (short)0;       // k<16: bw-weighted, k>=16: 0
                b2[k] = loQ ? (short)0 : qd[k];       // k>=16: dw-weighted
            }
            f32x4_t z = {0.f,0.f,0.f,0.f};
            f32x4_t a1 = __builtin_amdgcn_mfma_f32_16x16x32_bf16(afull, b1, z, 0,0,0);
            f32x4_t a2 = __builtin_amdgcn_mfma_f32_16x16x32_bf16(afull, b2, z, 0,0,0);
            #pragma unroll
            for (int rr = 0; rr < 4; ++rr) {
                int t = wid*16 + quad*4 + rr;
                int w = sb + row16 - t;
                if ((unsigned)w < 64u) {
                    unsigned pk = (unsigned)f2bf(a1[rr]) | ((unsigned)f2bf(a2[rr]) << 16);
                    SbL[t*65 + w] = pk;
                }
            }
        }
    }
    // per-lane t constants (TbL valid after phase-2 barrier)
    float hLbt, DbtR, hLdt, DdtR;
    {
        uint2 tt = TbL[lane + 63];
        hLbt = 0.5f * bflo(tt.x);  DbtR = bfhi(tt.x);
        hLdt = 0.5f * bflo(tt.y);  DdtR = bfhi(tt.y);
    }
    const float damC = cbuf2[64] - hLdt;
    __syncthreads();

    // ---- phase 4: zero wgtA (overlays projL/Qb/Qd, all dead now) ----
    for (int e = tid; e < 1088; e += 256) ((uint4*)wgtA)[e] = make_uint4(0,0,0,0);
    __syncthreads();

    // ---- phase 5 (combine): logits from tables + S, softmax exp ----
    {
        const int base = t0 + lane - 63;
        const int wbA = lane*136 + lane;    // wgtA band base for this t
        float sm = 0.f;
        #pragma unroll
        for (int it = 0; it < 16; ++it) {
            const int w = __builtin_amdgcn_readfirstlane(wid*16 + it);
            const float cw0 = cbuf2[w];
            uint2 tt = TbL[lane + w];
            unsigned sp = SbL[lane*65 + w];
            float Lbs = bflo(tt.x), Dbs = bfhi(tt.x);
            float Lds = bflo(tt.y), Dds = bfhi(tt.y);
            float S1 = bflo(sp), S2 = bfhi(sp);
            float bond = fmaf(Lbs, 0.5f, cw0) - hLbt;
            float tb = Dbs + DbtR;  tb = fmaf(-2.f, S1, tb);
            bond = fmaf(K2G, tb, bond);
            float dam = fmaf(Lds, 0.5f, damC);
            float td = Dds + DdtR;  td = fmaf(-2.f, S2, td);
            dam = fmaf(K2G, td, dam);
            float sig = __builtin_amdgcn_rcpf(1.f + __expf(-dam));
            float logit = fmaf(-10.f, sig, bond);
            float ex = (base + w >= 0) ? __expf(logit) : 0.f;
            sm += ex;
            wgtA[wbA + w] = f2bf(ex);
        }
        smL[wid*64 + lane] = sm;
    }
    __syncthreads();

    // ---- phase 6 (stage-3): out = wgtA(64x128) @ valL(128x64), banded MFMA ----
    const int waveM = wid >> 1, waveN = wid & 1;
    f32x4_t acc[2][2];
    #pragma unroll
    for (int i = 0; i < 2; ++i)
        #pragma unroll
        for (int j = 0; j < 2; ++j) { f32x4_t z = {0.f,0.f,0.f,0.f}; acc[i][j] = z; }
    #pragma unroll
    for (int kk = 0; kk < 3; ++kk) {
        const int k0 = waveM*32 + kk*32;
        bf16x8_t af[2], bfv[2];
        #pragma unroll
        for (int mt = 0; mt < 2; ++mt)
            af[mt] = *(const bf16x8_t*)(wgtA + (waveM*32 + mt*16 + row16)*136 + k0 + quad*8);
        #pragma unroll
        for (int nt = 0; nt < 2; ++nt) {
            int d = waveN*32 + nt*16 + row16;
            bf16x8_t bv;
            #pragma unroll
            for (int j = 0; j < 8; ++j)
                bv[j] = (short)valL[(k0 + quad*8 + j)*66 + d];
            bfv[nt] = bv;
        }
        #pragma unroll
        for (int mt = 0; mt < 2; ++mt)
            #pragma unroll
            for (int nt = 0; nt < 2; ++nt)
                acc[mt][nt] = __builtin_amdgcn_mfma_f32_16x16x32_bf16(
                    af[mt], bfv[nt], acc[mt][nt], 0, 0, 0);
    }
    #pragma unroll
    for (int mt = 0; mt < 2; ++mt)
        #pragma unroll
        for (int nt = 0; nt < 2; ++nt) {
            int d = waveN*32 + nt*16 + row16;
            #pragma unroll
            for (int rr = 0; rr < 4; ++rr) {
                int trel = waveM*32 + mt*16 + quad*4 + rr;
                float smt = smL[trel] + smL[64 + trel] + smL[128 + trel] + smL[192 + trel];
                float v = acc[mt][nt][rr] * __builtin_amdgcn_rcpf(smt);
                attb[((long long)(b*T_ + t0 + trel))*1024 + h*64 + d] = f2bf(v);
            }
        }
}

extern "C" void kernel_launch(void* const* d_in, const int* in_sizes, int n_in,
                              void* d_out, int out_size, void* d_ws, size_t ws_size,
                              hipStream_t stream) {
    const float* x    = (const float*)d_in[0];
    const float* Wd   = (const float*)d_in[1];
    const float* Wv   = (const float*)d_in[2];
    const float* rel  = (const float*)d_in[3];
    const float* sfw  = (const float*)d_in[4];
    const float* sfb  = (const float*)d_in[5];
    const float* ppw  = (const float*)d_in[6];
    const float* bow  = (const float*)d_in[7];
    const float* dow  = (const float*)d_in[8];
    const float* dob  = (const float*)d_in[9];
    const float* cpw  = (const float*)d_in[10];
    float* out = (float*)d_out;

    char* w = (char*)d_ws;
    unsigned short* xb      = (unsigned short*)(w);                 // 8,388,608 B
    unsigned short* wcat    = (unsigned short*)(w + 8388608);       // 3,145,728 B
    unsigned short* cprojb  = (unsigned short*)(w + 11534336);      // 2,097,152 B
    float*          cbuf2   = (float*)         (w + 13631488);      //     8,192 B
    unsigned short* projb   = (unsigned short*)(w + 13639680);      // 4,194,304 B
    unsigned short* valb    = (unsigned short*)(w + 17833984);      // 8,388,608 B
    unsigned short* attb    = (unsigned short*)(w + 26222592);      // 8,388,608 B

    prep_kernel<<<8193, 256, 0, stream>>>(
        x, Wv, cpw, Wd, sfw, rel, ppw, sfb, bow, dow, dob,
        xb, wcat + 512*1024, cprojb, wcat, cbuf2);
    // [projb | valb] = x @ [W_comb; W_val]^T : 384 blocks, XCD-swizzled
    gemm128<2><<<384, 256, 0, stream>>>(
        xb, wcat, (float*)nullptr, projb, valb, B_*T_, 1536, C_, 12);
    attn_kernel<<<dim3(T_/64, NH_, B_), 256, 0, stream>>>(
        projb, valb, cbuf2, bow, dow, attb);
    // out = att @ c_proj^T : fp32, 256 blocks, XCD-swizzled
    gemm128<0><<<256, 256, 0, stream>>>(
        attb, cprojb, out, (unsigned short*)nullptr, (unsigned short*)nullptr,
        B_*T_, C_, C_, 8);
}

// Round 11
// 162.401 us; speedup vs baseline: 1.1474x; 1.0612x over previous
//
#include <hip/hip_runtime.h>
#include <hip/hip_bf16.h>
#include <math.h>

#define B_ 2
#define T_ 2048
#define C_ 1024
#define NH_ 16
#define HS_ 64
#define BD_ 16
#define DELTA 64
#define K2G 0.3989422804f   // 1/sqrt(2*pi)

typedef __attribute__((ext_vector_type(8))) short bf16x8_t;
typedef __attribute__((ext_vector_type(4))) float f32x4_t;
typedef __attribute__((address_space(1))) const unsigned int GUI;
typedef __attribute__((address_space(3))) unsigned int LUI;

__device__ __forceinline__ unsigned short f2bf(float f) {
    unsigned u = __float_as_uint(f);
    u = u + 0x7fffu + ((u >> 16) & 1u);
    return (unsigned short)(u >> 16);
}
__device__ __forceinline__ float bf2f(unsigned short h) {
    return __uint_as_float(((unsigned)h) << 16);
}
__device__ __forceinline__ float bflo(unsigned u) { return __uint_as_float(u << 16); }
__device__ __forceinline__ float bfhi(unsigned u) { return __uint_as_float(u & 0xffff0000u); }
__device__ __forceinline__ void glds16(const unsigned short* g, unsigned short* l) {
    __builtin_amdgcn_global_load_lds((GUI*)g, (LUI*)l, 16, 0, 0);
}

// ---- prep: cvt + W_comb + per-w scalar constants ----
__global__ __launch_bounds__(256) void prep_kernel(
    const float* __restrict__ x, const float* __restrict__ wval,
    const float* __restrict__ cproj, const float* __restrict__ Wd,
    const float* __restrict__ sfw, const float* __restrict__ rel,
    const float* __restrict__ ppw, const float* __restrict__ sfb,
    const float* __restrict__ bw, const float* __restrict__ dw,
    const float* __restrict__ dob,
    unsigned short* __restrict__ xb, unsigned short* __restrict__ wvalb,
    unsigned short* __restrict__ cprojb, unsigned short* __restrict__ wc,
    float* __restrict__ cbuf2)
{
    const int bid = blockIdx.x;
    if (bid < 6144) {           // fp32 -> bf16
        const long long NX = (long long)B_*T_*C_;
        const long long NW = (long long)C_*C_;
        long long e = ((long long)bid * 256 + threadIdx.x) * 4;
        const float* src; unsigned short* dst; long long off;
        if (e < NX)            { src = x;     dst = xb;     off = e; }
        else if (e < NX + NW)  { src = wval;  dst = wvalb;  off = e - NX; }
        else                   { src = cproj; dst = cprojb; off = e - NX - NW; }
        float4 v = *(const float4*)(src + off);
        ushort4 o;
        o.x = f2bf(v.x); o.y = f2bf(v.y); o.z = f2bf(v.z); o.w = f2bf(v.w);
        *(ushort4*)(dst + off) = o;
    } else if (bid < 8192) {    // W_comb
        int idx = (bid - 6144) * 256 + threadIdx.x;
        int c = idx & 1023, row = idx >> 10;
        int h = row >> 5, j = row & 31;
        float s = 0.f;
        #pragma unroll
        for (int d = 0; d < 16; ++d) s += sfw[j*16 + d] * Wd[(h*16 + d)*1024 + c];
        wc[idx] = f2bf(s);
    } else {
        int tid = threadIdx.x;
        if (tid < 64) {
            float acc = 0.f;
            for (int j = 0; j < 16; ++j) {
                float c = sfb[j];
                #pragma unroll
                for (int d = 0; d < 16; ++d) c += rel[tid*16 + d] * ppw[j*16 + d];
                acc += bw[j] * fmaf(K2G*c, c, 0.5f*c);
            }
            cbuf2[tid] = acc;
        } else if (tid == 64) {
            float acc = dob[0];
            for (int j = 0; j < 16; ++j) {
                float c = sfb[16 + j];
                acc += dw[j] * fmaf(K2G*c, c, 0.5f*c);
            }
            cbuf2[64] = acc;
        }
    }
}

// ---- 64x128 tile GEMM, BK=64, m97 layout, XCD-swizzled flat grid ----
// Balanced grids: gemm1 768 blocks (3/CU), gemm2 512 blocks (2/CU).
// MODE 0: fp32 out (Cf, pitch N). MODE 2: split col<512 -> Cb1 bf16 pitch 512,
// col>=512 -> Cb2 bf16 pitch 1024.
template<int MODE>
__global__ __launch_bounds__(256, 3) void gemm64(
    const unsigned short* __restrict__ A,
    const unsigned short* __restrict__ Bw,
    float* __restrict__ Cf, unsigned short* __restrict__ Cb1,
    unsigned short* __restrict__ Cb2,
    int M, int N, int K, int nxt)
{
    __shared__ unsigned short As[64*64];    //  8 KB
    __shared__ unsigned short Bs[128*64];   // 16 KB
    const int nblk = gridDim.x;
    const int bid = blockIdx.x;
    const int l = (bid & 7) * (nblk >> 3) + (bid >> 3);   // XCD-contiguous
    const int nb = l % nxt, mb = l / nxt;
    const int m0 = mb * 64, n0 = nb * 128;
    const int tid = threadIdx.x;
    const int lane = tid & 63;
    const int wid = tid >> 6;
    const int waveM = wid >> 1, waveN = wid & 1;
    const int row16 = lane & 15, quad = lane >> 4;
    const int wbase = wid * 512;

    long long gA[2], gB[4];
    #pragma unroll
    for (int q = 0; q < 2; ++q) {
        int c = q*256 + tid, r = c >> 3, col = (c & 7) * 8;
        gA[q] = (long long)(m0 + r) * K + col;
    }
    #pragma unroll
    for (int q = 0; q < 4; ++q) {
        int c = q*256 + tid, r = c >> 3, col = (c & 7) * 8;
        gB[q] = (long long)(n0 + r) * K + col;
    }

    f32x4_t acc[2][4];
    #pragma unroll
    for (int i = 0; i < 2; ++i)
        #pragma unroll
        for (int j = 0; j < 4; ++j) { f32x4_t z = {0.f,0.f,0.f,0.f}; acc[i][j] = z; }

    for (int k0 = 0; k0 < K; k0 += 64) {
        #pragma unroll
        for (int q = 0; q < 2; ++q)
            glds16(A + gA[q] + k0, As + q*2048 + wbase);
        #pragma unroll
        for (int q = 0; q < 4; ++q)
            glds16(Bw + gB[q] + k0, Bs + q*2048 + wbase);
        __syncthreads();
        #pragma unroll
        for (int kk = 0; kk < 2; ++kk) {
            bf16x8_t af[2], bfv[4];
            #pragma unroll
            for (int mt = 0; mt < 2; ++mt)
                af[mt] = *(const bf16x8_t*)(As + (waveM*32 + mt*16 + row16)*64
                                               + (kk*4 + quad)*8);
            #pragma unroll
            for (int nt = 0; nt < 4; ++nt)
                bfv[nt] = *(const bf16x8_t*)(Bs + (waveN*64 + nt*16 + row16)*64
                                                + (kk*4 + quad)*8);
            #pragma unroll
            for (int mt = 0; mt < 2; ++mt)
                #pragma unroll
                for (int nt = 0; nt < 4; ++nt)
                    acc[mt][nt] = __builtin_amdgcn_mfma_f32_16x16x32_bf16(
                        af[mt], bfv[nt], acc[mt][nt], 0, 0, 0);
        }
        __syncthreads();
    }
    #pragma unroll
    for (int mt = 0; mt < 2; ++mt)
        #pragma unroll
        for (int nt = 0; nt < 4; ++nt) {
            int col = n0 + waveN*64 + nt*16 + row16;
            #pragma unroll
            for (int rr = 0; rr < 4; ++rr) {
                int row = m0 + waveM*32 + mt*16 + quad*4 + rr;
                float v = acc[mt][nt][rr];
                if (MODE == 0) {
                    Cf[(long long)row * N + col] = v;
                } else {
                    if (col < 512) Cb1[(long long)row * 512 + col] = f2bf(v);
                    else           Cb2[(long long)row * 1024 + (col - 512)] = f2bf(v);
                }
            }
        }
}

// ---- windowed attention v10: bilinear decomposition (unchanged from r10) ----
__global__ __launch_bounds__(256, 3) void attn_kernel(
    const unsigned short* __restrict__ projb,  // (B*T, 512) bf16
    const unsigned short* __restrict__ valb,   // (B*T, 1024) bf16
    const float* __restrict__ cbuf2,           // [0..63] bond const; [64] damage const
    const float* __restrict__ bw,              // (16,)
    const float* __restrict__ dw,              // (16,)
    unsigned short* __restrict__ attb)         // (B*T, 1024) bf16
{
    __shared__ __align__(16) unsigned char smem[53928];
    unsigned short* projL = (unsigned short*)(smem);            // 127x40 ush
    unsigned short* Qb    = (unsigned short*)(smem + 10160);    // 128x16 ush
    unsigned short* Qd    = (unsigned short*)(smem + 14256);    // 128x16 ush
    unsigned short* wgtA  = (unsigned short*)(smem);            // 64x136 ush (overlays)
    unsigned short* valL  = (unsigned short*)(smem + 18352);    // 128x66 ush
    unsigned*       SbL   = (unsigned*)(smem + 35248);          // 64x65 dw
    uint2*          TbL   = (uint2*)(smem + 51888);             // 127 x uint2
    float*          smL   = (float*)(smem + 52904);             // 4x64
    const int t0 = blockIdx.x * 64;
    const int h = blockIdx.y, b = blockIdx.z;
    const int tid = threadIdx.x;
    const int lane = tid & 63, wid = tid >> 6;
    const int row16 = lane & 15, quad = lane >> 4;

    // phase 1: stage projL + valL
    for (int e = tid; e < 128*16; e += 256) {
        int ls = e >> 4, d4 = e & 15;
        int s = t0 - 63 + ls;
        ushort4 v = make_ushort4(0, 0, 0, 0);
        if (s >= 0 && ls < 127)
            v = *(const ushort4*)(valb + (long long)(b*T_ + s)*1024 + h*64 + d4*4);
        *(ushort4*)(valL + ls*66 + d4*4) = v;
    }
    for (int e = tid; e < 127*4; e += 256) {
        int r = e >> 2, c = e & 3;
        int s = t0 - 63 + r;
        uint4 v = make_uint4(0, 0, 0, 0);
        if (s >= 0)
            v = *(const uint4*)(projb + (long long)(b*T_ + s)*512 + h*32 + c*8);
        *(uint4*)(projL + r*40 + c*8) = v;
    }
    __syncthreads();

    // phase 2: row tables + weighted rows
    {
        int r = tid >> 1, hf = tid & 1;
        bf16x8_t ob, od;
        if (r < 127) {
            bf16x8_t vb = *(const bf16x8_t*)(projL + r*40 + hf*8);
            bf16x8_t vd = *(const bf16x8_t*)(projL + r*40 + 16 + hf*8);
            #pragma unroll
            for (int k = 0; k < 8; ++k) {
                int j = hf*8 + k;
                ob[k] = (short)f2bf(bf2f((unsigned short)vb[k]) * bw[j]);
                od[k] = (short)f2bf(bf2f((unsigned short)vd[k]) * dw[j]);
            }
        } else {
            #pragma unroll
            for (int k = 0; k < 8; ++k) { ob[k] = 0; od[k] = 0; }
        }
        *(bf16x8_t*)(Qb + r*16 + hf*8) = ob;
        *(bf16x8_t*)(Qd + r*16 + hf*8) = od;
    }
    if (tid < 127) {
        int r = tid;
        float Lb = 0.f, Db = 0.f, Ld = 0.f, Dd = 0.f;
        #pragma unroll
        for (int g = 0; g < 4; ++g) {
            bf16x8_t v = *(const bf16x8_t*)(projL + r*40 + g*8);
            #pragma unroll
            for (int k = 0; k < 8; ++k) {
                float a = bf2f((unsigned short)v[k]);
                int j = g*8 + k;
                if (j < 16) { float wj = bw[j];     Lb += wj*a; Db += wj*a*a; }
                else        { float wj = dw[j-16];  Ld += wj*a; Dd += wj*a*a; }
            }
        }
        uint2 o;
        o.x = (unsigned)f2bf(Lb) | ((unsigned)f2bf(Db) << 16);
        o.y = (unsigned)f2bf(Ld) | ((unsigned)f2bf(Dd) << 16);
        TbL[r] = o;
    }
    __syncthreads();

    // phase 3: S1/S2 via MFMA, banded write to SbL
    {
        const int trow = 63 + wid*16 + row16;
        bf16x8_t afull = *(const bf16x8_t*)(projL + trow*40 + quad*8);
        const bool loQ = quad < 2;
        #pragma unroll
        for (int ts = 0; ts < 6; ++ts) {
            const int sb = wid*16 + ts*16;
            if (sb >= 128) continue;
            const int srow = sb + row16;
            bf16x8_t qb = *(const bf16x8_t*)(Qb + srow*16 + (quad & 1)*8);
            bf16x8_t qd = *(const bf16x8_t*)(Qd + srow*16 + (quad & 1)*8);
            bf16x8_t b1, b2;
            #pragma unroll
            for (int k = 0; k < 8; ++k) {
                b1[k] = loQ ? qb[k] : (short)0;
                b2[k] = loQ ? (short)0 : qd[k];
            }
            f32x4_t z = {0.f,0.f,0.f,0.f};
            f32x4_t a1 = __builtin_amdgcn_mfma_f32_16x16x32_bf16(afull, b1, z, 0,0,0);
            f32x4_t a2 = __builtin_amdgcn_mfma_f32_16x16x32_bf16(afull, b2, z, 0,0,0);
            #pragma unroll
            for (int rr = 0; rr < 4; ++rr) {
                int t = wid*16 + quad*4 + rr;
                int w = sb + row16 - t;
                if ((unsigned)w < 64u) {
                    unsigned pk = (unsigned)f2bf(a1[rr]) | ((unsigned)f2bf(a2[rr]) << 16);
                    SbL[t*65 + w] = pk;
                }
            }
        }
    }
    float hLbt, DbtR, hLdt, DdtR;
    {
        uint2 tt = TbL[lane + 63];
        hLbt = 0.5f * bflo(tt.x);  DbtR = bfhi(tt.x);
        hLdt = 0.5f * bflo(tt.y);  DdtR = bfhi(tt.y);
    }
    const float damC = cbuf2[64] - hLdt;
    __syncthreads();

    // phase 4: zero wgtA (overlays projL/Qb/Qd)
    for (int e = tid; e < 1088; e += 256) ((uint4*)wgtA)[e] = make_uint4(0,0,0,0);
    __syncthreads();

    // phase 5: logits from tables + S, softmax exp
    {
        const int base = t0 + lane - 63;
        const int wbA = lane*136 + lane;
        float sm = 0.f;
        #pragma unroll
        for (int it = 0; it < 16; ++it) {
            const int w = __builtin_amdgcn_readfirstlane(wid*16 + it);
            const float cw0 = cbuf2[w];
            uint2 tt = TbL[lane + w];
            unsigned sp = SbL[lane*65 + w];
            float Lbs = bflo(tt.x), Dbs = bfhi(tt.x);
            float Lds = bflo(tt.y), Dds = bfhi(tt.y);
            float S1 = bflo(sp), S2 = bfhi(sp);
            float bond = fmaf(Lbs, 0.5f, cw0) - hLbt;
            float tb = Dbs + DbtR;  tb = fmaf(-2.f, S1, tb);
            bond = fmaf(K2G, tb, bond);
            float dam = fmaf(Lds, 0.5f, damC);
            float td = Dds + DdtR;  td = fmaf(-2.f, S2, td);
            dam = fmaf(K2G, td, dam);
            float sig = __builtin_amdgcn_rcpf(1.f + __expf(-dam));
            float logit = fmaf(-10.f, sig, bond);
            float ex = (base + w >= 0) ? __expf(logit) : 0.f;
            sm += ex;
            wgtA[wbA + w] = f2bf(ex);
        }
        smL[wid*64 + lane] = sm;
    }
    __syncthreads();

    // phase 6: out = wgtA(64x128) @ valL(128x64), banded MFMA
    const int waveM = wid >> 1, waveN = wid & 1;
    f32x4_t acc[2][2];
    #pragma unroll
    for (int i = 0; i < 2; ++i)
        #pragma unroll
        for (int j = 0; j < 2; ++j) { f32x4_t z = {0.f,0.f,0.f,0.f}; acc[i][j] = z; }
    #pragma unroll
    for (int kk = 0; kk < 3; ++kk) {
        const int k0 = waveM*32 + kk*32;
        bf16x8_t af[2], bfv[2];
        #pragma unroll
        for (int mt = 0; mt < 2; ++mt)
            af[mt] = *(const bf16x8_t*)(wgtA + (waveM*32 + mt*16 + row16)*136 + k0 + quad*8);
        #pragma unroll
        for (int nt = 0; nt < 2; ++nt) {
            int d = waveN*32 + nt*16 + row16;
            bf16x8_t bv;
            #pragma unroll
            for (int j = 0; j < 8; ++j)
                bv[j] = (short)valL[(k0 + quad*8 + j)*66 + d];
            bfv[nt] = bv;
        }
        #pragma unroll
        for (int mt = 0; mt < 2; ++mt)
            #pragma unroll
            for (int nt = 0; nt < 2; ++nt)
                acc[mt][nt] = __builtin_amdgcn_mfma_f32_16x16x32_bf16(
                    af[mt], bfv[nt], acc[mt][nt], 0, 0, 0);
    }
    #pragma unroll
    for (int mt = 0; mt < 2; ++mt)
        #pragma unroll
        for (int nt = 0; nt < 2; ++nt) {
            int d = waveN*32 + nt*16 + row16;
            #pragma unroll
            for (int rr = 0; rr < 4; ++rr) {
                int trel = waveM*32 + mt*16 + quad*4 + rr;
                float smt = smL[trel] + smL[64 + trel] + smL[128 + trel] + smL[192 + trel];
                float v = acc[mt][nt][rr] * __builtin_amdgcn_rcpf(smt);
                attb[((long long)(b*T_ + t0 + trel))*1024 + h*64 + d] = f2bf(v);
            }
        }
}

extern "C" void kernel_launch(void* const* d_in, const int* in_sizes, int n_in,
                              void* d_out, int out_size, void* d_ws, size_t ws_size,
                              hipStream_t stream) {
    const float* x    = (const float*)d_in[0];
    const float* Wd   = (const float*)d_in[1];
    const float* Wv   = (const float*)d_in[2];
    const float* rel  = (const float*)d_in[3];
    const float* sfw  = (const float*)d_in[4];
    const float* sfb  = (const float*)d_in[5];
    const float* ppw  = (const float*)d_in[6];
    const float* bow  = (const float*)d_in[7];
    const float* dow  = (const float*)d_in[8];
    const float* dob  = (const float*)d_in[9];
    const float* cpw  = (const float*)d_in[10];
    float* out = (float*)d_out;

    char* w = (char*)d_ws;
    unsigned short* xb      = (unsigned short*)(w);                 // 8,388,608 B
    unsigned short* wcat    = (unsigned short*)(w + 8388608);       // 3,145,728 B
    unsigned short* cprojb  = (unsigned short*)(w + 11534336);      // 2,097,152 B
    float*          cbuf2   = (float*)         (w + 13631488);      //     8,192 B
    unsigned short* projb   = (unsigned short*)(w + 13639680);      // 4,194,304 B
    unsigned short* valb    = (unsigned short*)(w + 17833984);      // 8,388,608 B
    unsigned short* attb    = (unsigned short*)(w + 26222592);      // 8,388,608 B

    prep_kernel<<<8193, 256, 0, stream>>>(
        x, Wv, cpw, Wd, sfw, rel, ppw, sfb, bow, dow, dob,
        xb, wcat + 512*1024, cprojb, wcat, cbuf2);
    // [projb | valb] = x @ [W_comb; W_val]^T : 64x128 tiles, 768 blocks (3/CU)
    gemm64<2><<<768, 256, 0, stream>>>(
        xb, wcat, (float*)nullptr, projb, valb, B_*T_, 1536, C_, 12);
    attn_kernel<<<dim3(T_/64, NH_, B_), 256, 0, stream>>>(
        projb, valb, cbuf2, bow, dow, attb);
    // out = att @ c_proj^T : fp32, 64x128 tiles, 512 blocks (2/CU)
    gemm64<0><<<512, 256, 0, stream>>>(
        attb, cprojb, out, (unsigned short*)nullptr, (unsigned short*)nullptr,
        B_*T_, C_, C_, 8);
}